// Round 5
// baseline (77.904 us; speedup 1.0000x reference)
//
#include <hip/hip_runtime.h>
#include <math.h>

#define HW 1024
#define NB 16
#define TMAXS 1024

typedef unsigned long long ull;

__device__ __forceinline__ double u2d(ull u) {
  return __longlong_as_double((long long)u);
}
__device__ __forceinline__ ull d2u(double d) {
  return (ull)__double_as_longlong(d);
}

// f = 0.5*g + 0.5*h, key = exp(-f/sqrt(32)) — bit-identical op order to the
// reference (validated absmax==0 in rounds 1-4).
__device__ __forceinline__ float keyval(float g, float h) {
#pragma clang fp contract(off)
  const float INV = 0.17677669529663687f; // fl32(1/sqrt(32))
  float f = 0.5f * g + 0.5f * h;
  return expf(-f * INV);
}

// One DPP reduction stage on a packed-f64 value (nonnegative; disabled
// source lanes contribute 0.0 = identity). Chain validated rounds 2-4.
template <int CTRL>
__device__ __forceinline__ double dpp_fmax64(double x) {
  ull u = d2u(x);
  int lo = (int)(unsigned)u;
  int hi = (int)(unsigned)(u >> 32);
  int lo2 = __builtin_amdgcn_update_dpp(0, lo, CTRL, 0xF, 0xF, false);
  int hi2 = __builtin_amdgcn_update_dpp(0, hi, CTRL, 0xF, 0xF, false);
  double y = u2d(((ull)(unsigned)hi2 << 32) | (unsigned)lo2);
  return fmax(x, y);
}

// ---------------------------------------------------------------------------
// Fused per-batch A* + backtrack, one wave per batch. Incremental level1
// argmax (R4-validated) restructured to hide the big reduce under the LDS
// read latency:
//   max(S_i) = max( R_stale                      [stale level1, lane gp
//                                                 zeroed — pure VALU 6-stage
//                                                 DPP, runs DURING the ring/
//                                                 group ds_read window,
//                                                 readlane'd to SGPRs]
//                 , patched group-gp cells       [lanes 16..31, pop patched]
//                 , fresh ring pks               [lanes 0..7, increases] )
//   Tail after reads land: expf/pack + short reduce over lanes 0..31 only
//   (shr1/2/4/8 + bcast15 fold -> lane 31) + v_max_f64 vs R_stale (SGPR
//   pair) + readlane(31).
//   level1 maintenance (exact, off critical path): lane8 zeroes level1[gp];
//   group lanes re-atomicMax patched S_{i-1} keys; relax lanes atomicMax
//   fresh pks. All post-zero ops are increases -> order-free. DS ops of one
//   wave execute in program order; stale re-read issued right after the
//   atomics (slack: only needed by next iter's hidden DPP chain).
// Numerics / relax condition / early-exit / fused backtrack: byte-identical
// to rounds 1-4 (validated absmax 0).
// ---------------------------------------------------------------------------
extern "C" __global__ void __launch_bounds__(64) astar_fused(
    const float* __restrict__ cm_g, const float* __restrict__ sm_g,
    const float* __restrict__ gm_g, const float* __restrict__ om_g,
    float* __restrict__ out) {
#pragma clang fp contract(off)
  const int b = blockIdx.x;
  const int lane = threadIdx.x;

  __shared__ __align__(16) ull key2[HW];     // packed (f64(key) | 1023-idx)
  __shared__ __align__(16) float4 gch[HW];   // {g, cm, g+cm, h_full}
  __shared__ __align__(16) unsigned flg[HW]; // bit0 free, bit1 open, bit2 hist
  __shared__ __align__(16) unsigned par[HW]; // parent | mark bit31
  __shared__ __align__(16) ull level1[64];   // per-16-cell-group max
  const float* gchf = (const float*)gch;

  const float* cm = cm_g + b * HW;
  const float* sm = sm_g + b * HW;
  const float* gm = gm_g + b * HW;
  const float* om = om_g + b * HW;

  // ---- init pass 1: vectorized loads, locate goal/start ----
  float4 c4[4], o4[4];
  int gi = -1, si = -1;
#pragma unroll
  for (int q = 0; q < 4; ++q) {
    const int base = q * 256 + lane * 4;
    c4[q] = *(const float4*)(cm + base);
    o4[q] = *(const float4*)(om + base);
    const float4 s4 = *(const float4*)(sm + base);
    const float4 g4 = *(const float4*)(gm + base);
    const float sv[4] = {s4.x, s4.y, s4.z, s4.w};
    const float gv[4] = {g4.x, g4.y, g4.z, g4.w};
#pragma unroll
    for (int j = 0; j < 4; ++j) {
      if (gv[j] > 0.5f) gi = base + j;
      if (sv[j] > 0.5f) si = base + j;
    }
  }
#pragma unroll
  for (int m = 32; m >= 1; m >>= 1) {
    const int og = __shfl_xor(gi, m, 64);
    const int os = __shfl_xor(si, m, 64);
    gi = (og > gi) ? og : gi;
    si = (os > si) ? os : si;
  }
  const int goal = gi, start = si;

  // ---- init pass 2: h (exact ref op order), state arrays, level1 ----
  level1[lane] = 0ull; // before the atomics below (same array: order kept)
  const float grf = (float)(goal >> 5), gcf = (float)(goal & 31);
#pragma unroll
  for (int q = 0; q < 4; ++q) {
    const int base = q * 256 + lane * 4;
    const float cv[4] = {c4[q].x, c4[q].y, c4[q].z, c4[q].w};
    const float ov[4] = {o4[q].x, o4[q].y, o4[q].z, o4[q].w};
    ull pk[4];
    unsigned fv[4];
#pragma unroll
    for (int j = 0; j < 4; ++j) {
      const int cell = base + j;
      const float rr = (float)(cell >> 5), cc = (float)(cell & 31);
      const float dr = fabsf(rr - grf), dc = fabsf(cc - gcf);
      const float h0 = (dr + dc) - fminf(dr, dc); // exact (small ints)
      const float euc = sqrtf(dr * dr + dc * dc); // exact radicand
      const float t1 = 0.001f * euc;              // contract off: no fma
      const float hh = h0 + t1;
      const float hf = hh + cv[j];
      gch[cell] = make_float4(0.0f, cv[j], cv[j], hf);
      fv[j] = (ov[j] > 0.5f) ? 1u : 0u;
      pk[j] = (ull)(1023 - cell);
      if (cell == start) {
        fv[j] |= 2u; // open = start map
        pk[j] |= d2u((double)keyval(0.0f, hf));
      }
      atomicMax(&level1[cell >> 4], pk[j]);
    }
    *(uint4*)&flg[base] = make_uint4(fv[0], fv[1], fv[2], fv[3]);
    *(uint4*)&par[base] =
        make_uint4((unsigned)goal, (unsigned)goal, (unsigned)goal, (unsigned)goal);
    ulonglong2 k01, k23;
    k01.x = pk[0]; k01.y = pk[1];
    k23.x = pk[2]; k23.y = pk[3];
    *(ulonglong2*)&key2[base] = k01;
    *(ulonglong2*)&key2[base + 2] = k23;
  }
  __builtin_amdgcn_wave_barrier();
  ull stale = level1[lane]; // S_{-1} group maxes

  int dro = 0, dco = 0;
  if (lane < 8) {
    const int k = (lane < 4) ? lane : lane + 1; // skip center
    dro = k / 3 - 1;
    dco = k % 3 - 1;
  }
  const bool grpLane = (lane >= 16) && (lane < 32);

  int sel = start; // step-0 argmax: start is the only open cell
  bool reached = false;

#pragma unroll 1
  for (int step = 0; step < TMAXS; ++step) {
    if (sel == goal) { reached = true; break; }
    const int gp = sel >> 4;

    // -- DS phase 1: issue ALL reads; zero popped group's level1 --
    const float g2 = gchf[4 * sel + 2]; // broadcast: g[sel]+cm[sel]
    int n = -1;
    if (lane < 8) {
      const int nr = (sel >> 5) + dro, nc = (sel & 31) + dco;
      if ((unsigned)nr < 32u && (unsigned)nc < 32u) n = (nr << 5) | nc;
    } else if (lane == 8) {
      n = sel;
    }
    unsigned f = 0;
    if (n >= 0) f = flg[n];
    float4 v = make_float4(0.f, 0.f, 0.f, 0.f);
    if (lane < 8 && n >= 0) v = gch[n];
    ull gc = 0ull;
    if (grpLane) {
      const int gcell = gp * 16 + (lane - 16);
      gc = key2[gcell]; // S_{i-1} (read precedes this iter's key2 writes)
      if (gcell == sel) gc = (ull)(1023 - sel); // patch the pop
    }
    if (lane == 8) level1[gp] = 0ull;

    // -- hidden under the DS latency: full DPP reduce over stale level1
    //    (group gp excluded), landed into SGPRs --
    double Rs = (lane == gp) ? 0.0 : u2d(stale);
    Rs = dpp_fmax64<0x111>(Rs); // row_shr:1
    Rs = dpp_fmax64<0x112>(Rs); // row_shr:2
    Rs = dpp_fmax64<0x114>(Rs); // row_shr:4
    Rs = dpp_fmax64<0x118>(Rs); // row_shr:8
    Rs = dpp_fmax64<0x142>(Rs); // row_bcast:15
    Rs = dpp_fmax64<0x143>(Rs); // row_bcast:31
    const ull rsu = d2u(Rs);
    const int rlo = __builtin_amdgcn_readlane((int)(unsigned)rsu, 63);
    const int rhi = __builtin_amdgcn_readlane((int)(unsigned)(rsu >> 32), 63);
    const double Rsg = u2d(((ull)(unsigned)rhi << 32) | (unsigned)rlo);

    // -- reads land: relax compute + writes + level1 maintenance --
    bool updv = false;
    ull pk = 0ull;
    if (lane < 8 && n >= 0) {
      updv = (f & 1u) && (((f & 6u) == 0u) || (((f & 2u) != 0u) && (v.x > g2)));
      if (updv) pk = d2u((double)keyval(g2, v.w)) | (ull)(1023 - n);
    }
    if (updv) {
      gch[n] = make_float4(g2, v.y, g2 + v.y, v.w);
      par[n] = (unsigned)sel;
    }
    if (updv || lane == 8) {
      flg[n] = (lane == 8) ? ((f | 4u) & ~2u) : (f | 2u);
      key2[n] = (lane == 8) ? (ull)(1023 - sel) : pk;
    }
    if (grpLane) atomicMax(&level1[gp], gc); // rebuild popped group
    if (updv) atomicMax(&level1[n >> 4], pk);

    // -- stale snapshot of level1(S_i) for next iter (after all writes;
    //    consumed only by next iter's hidden chain -> latency slack) --
    stale = level1[lane];

    // -- short reduce over lanes 0..31 (ring pks + patched group cells) --
    double m = 0.0;
    if (grpLane) m = u2d(gc);
    if (updv) m = u2d(pk);
    m = dpp_fmax64<0x111>(m); // row_shr:1
    m = dpp_fmax64<0x112>(m); // row_shr:2
    m = dpp_fmax64<0x114>(m); // row_shr:4
    m = dpp_fmax64<0x118>(m); // row_shr:8  (lane15=max(0..15), lane31=max(16..31))
    m = dpp_fmax64<0x142>(m); // row_bcast:15 fold -> lane31 = max(0..31)
    m = fmax(m, Rsg);         // fold stale part (SGPR pair)

    const int lo31 = __builtin_amdgcn_readlane((int)(unsigned)d2u(m), 31);
    sel = 1023 - (lo31 & 1023);
    __builtin_amdgcn_wave_barrier();
  }
  if (reached && lane == 0) flg[goal] |= 4u; // hist includes goal
  __builtin_amdgcn_wave_barrier();

  // ---- fused backtrack (lane 0): mark path via par bit31 ----
  if (lane == 0) {
    const unsigned pv = par[goal];
    par[goal] = pv | 0x80000000u; // path starts as goal one-hot
    unsigned loc = pv & 1023u;
#pragma unroll 1
    for (int i = 0; i < HW; ++i) {
      const unsigned w = par[loc];
      if (w & 0x80000000u) break; // deterministic replay of marked cells
      par[loc] = w | 0x80000000u;
      loc = w & 1023u;
    }
  }
  __builtin_amdgcn_wave_barrier();

  // ---- epilogue: hist + path ----
#pragma unroll
  for (int q = 0; q < 4; ++q) {
    const int base = q * 256 + lane * 4;
    float4 hv, pv;
    hv.x = (flg[base + 0] & 4u) ? 1.0f : 0.0f;
    hv.y = (flg[base + 1] & 4u) ? 1.0f : 0.0f;
    hv.z = (flg[base + 2] & 4u) ? 1.0f : 0.0f;
    hv.w = (flg[base + 3] & 4u) ? 1.0f : 0.0f;
    pv.x = (par[base + 0] >> 31) ? 1.0f : 0.0f;
    pv.y = (par[base + 1] >> 31) ? 1.0f : 0.0f;
    pv.z = (par[base + 2] >> 31) ? 1.0f : 0.0f;
    pv.w = (par[base + 3] >> 31) ? 1.0f : 0.0f;
    *(float4*)(out + b * HW + base) = hv;
    *(float4*)(out + NB * HW + b * HW + base) = pv;
  }
}

extern "C" void kernel_launch(void* const* d_in, const int* in_sizes, int n_in,
                              void* d_out, int out_size, void* d_ws,
                              size_t ws_size, hipStream_t stream) {
  const float* cm = (const float*)d_in[0];
  const float* sm = (const float*)d_in[1];
  const float* gm = (const float*)d_in[2];
  const float* om = (const float*)d_in[3];
  float* out = (float*)d_out;
  hipLaunchKernelGGL(astar_fused, dim3(NB), dim3(64), 0, stream, cm, sm, gm,
                     om, out);
}